// Round 6
// baseline (138.719 us; speedup 1.0000x reference)
//
#include <hip/hip_runtime.h>
#include <hip/hip_cooperative_groups.h>

namespace cg = cooperative_groups;

// MinibatchDiscrimination: B=512, IN=512, OUT=64, KD=8 (fp32 in/out)
// out[i, 0:512] = x[i, :]
// out[i, 512+o] = sum_j exp(-sum_k |M[i,o,k] - M[j,o,k]|),  M = x @ T
//
// R6: ONE cooperative kernel, grid 256 x 512thr (8 waves/CU, co-resident).
//  phase 1: Mt[o][i][k] computed ONCE (block = 64i x 16oc tile; waves 0..3 do
//           MFMA 16x16x32 bf16, A from global fp32 packed in-reg, B staged
//           transposed in LDS; C tile -> LDS -> fully-coalesced float4 Mt
//           stores). Waves 4..7 copy x -> out[:,0:512) meanwhile.
//  grid.sync()  (cooperative; device-scope visibility for Mt)
//  phase 2: pairs per (o, ic): full 16KB o-slice staged coalesced to LDS,
//           wave-uniform broadcast reads, 2 i/thread, cross-wave LDS
//           reduction, exclusive plain store. No atomics anywhere.

#define B_    512
#define IN_   512
#define OUT_  64
#define KD_   8
#define ROW_  576
#define ROW4_ 144

typedef short short8 __attribute__((ext_vector_type(8)));
typedef float f32x4  __attribute__((ext_vector_type(4)));

__device__ __forceinline__ unsigned short f2bf(float f) {
    return (unsigned short)((__float_as_uint(f) + 0x8000u) >> 16);
}
__device__ __forceinline__ unsigned pack_bf2(float lo, float hi) {
    unsigned a = (__float_as_uint(lo) + 0x8000u) >> 16;
    unsigned b = (__float_as_uint(hi) + 0x8000u) & 0xFFFF0000u;
    return a | b;
}

__global__ __launch_bounds__(512)
void fused_coop_kernel(const float* __restrict__ x, const float* __restrict__ T,
                       float* __restrict__ out, float* __restrict__ Mt) {
    // phase-1 view: Tt 16x520 ushort (16640 B) + Cs 64x17 f32 (4352 B)
    // phase-2 view: s 512x8 f32 (16384 B) + s2 8x128 f32 (4096 B)
    __shared__ __align__(16) char smem[21504];
    unsigned short (*Tt)[520] = (unsigned short(*)[520])smem;
    float (*Cs)[17]           = (float(*)[17])(smem + 16640);
    float (*s)[KD_]           = (float(*)[KD_])smem;
    float (*s2)[128]          = (float(*)[128])(smem + 16384);

    cg::grid_group grid = cg::this_grid();
    int t    = threadIdx.x;
    int bx   = blockIdx.x;
    int lane = t & 63, w = t >> 6;
    int r    = lane & 15, q = lane >> 4;

    // ---------------- phase 1: Mt[o][i][k], computed once -------------------
    {
        int nb = bx & 31, ib = bx >> 5;
        int n0 = nb * 16;

        // stage Tt[c][k] = bf16(T[k][n0+c]); 4 rows x 16 cols per wave-instr
        int c  = t & 15;
        int kb = t >> 4;                 // 0..31
        #pragma unroll
        for (int p = 0; p < 16; ++p) {
            int k = kb + p * 32;
            Tt[c][k] = f2bf(T[k * 512 + n0 + c]);
        }
        __syncthreads();

        if (w < 4) {
            int i0 = ib * 64 + w * 16;
            const float* pa = x + (i0 + r) * 512 + q * 8;
            f32x4 acc = {0.f, 0.f, 0.f, 0.f};
            #pragma unroll
            for (int kt = 0; kt < 16; ++kt) {
                float4 f0 = *(const float4*)(pa + kt * 32);
                float4 f1 = *(const float4*)(pa + kt * 32 + 4);
                union { unsigned u[4]; short8 v; } A;
                A.u[0] = pack_bf2(f0.x, f0.y);
                A.u[1] = pack_bf2(f0.z, f0.w);
                A.u[2] = pack_bf2(f1.x, f1.y);
                A.u[3] = pack_bf2(f1.z, f1.w);
                short8 Bv = *(const short8*)&Tt[r][q * 8 + kt * 32];
                acc = __builtin_amdgcn_mfma_f32_16x16x32_bf16(A.v, Bv, acc, 0, 0, 0);
            }
            // C/D map: value rr of lane -> row q*4+rr, col r
            #pragma unroll
            for (int rr = 0; rr < 4; ++rr)
                Cs[w * 16 + q * 4 + rr][r] = acc[rr];
        } else {
            // side job: x -> out cols [0,512); 256 float4 per block
            int v  = bx * 256 + (t - 256);     // [0, 65536)
            int i  = v >> 7;
            int c4 = v & 127;
            ((float4*)out)[i * ROW4_ + c4] = ((const float4*)x)[v];
        }
        __syncthreads();

        // coalesced Mt write: o-slices o = nb*2 + h, 64 i x 8 k each (2 KB)
        if (t < 256) {
            int h   = t >> 7;
            int idx = t & 127;
            int ii  = idx >> 1;
            int kq  = (idx & 1) * 4;
            int o   = nb * 2 + h;
            float4 v;
            v.x = Cs[ii][h * 8 + kq + 0];
            v.y = Cs[ii][h * 8 + kq + 1];
            v.z = Cs[ii][h * 8 + kq + 2];
            v.w = Cs[ii][h * 8 + kq + 3];
            *(float4*)(Mt + o * (B_ * KD_) + (ib * 64 + ii) * KD_ + kq) = v;
        }
    }

    __threadfence();
    grid.sync();

    // ---------------- phase 2: all-pairs L1 + exp ---------------------------
    int o  = bx >> 2;
    int ic = bx & 3;
    const float* base = Mt + o * (B_ * KD_);

    ((float4*)s)[t]       = ((const float4*)base)[t];
    ((float4*)s)[t + 512] = ((const float4*)base)[t + 512];
    __syncthreads();

    float mi[2][KD_];
    #pragma unroll
    for (int ii = 0; ii < 2; ++ii) {
        int i = ic * 128 + lane + ii * 64;
        float4 lo = *(const float4*)&s[i][0];
        float4 hi = *(const float4*)&s[i][4];
        mi[ii][0] = lo.x; mi[ii][1] = lo.y; mi[ii][2] = lo.z; mi[ii][3] = lo.w;
        mi[ii][4] = hi.x; mi[ii][5] = hi.y; mi[ii][6] = hi.z; mi[ii][7] = hi.w;
    }

    float acc0 = 0.f, acc1 = 0.f;
    const float* sj = &s[w * 64][0];         // wave-uniform -> LDS broadcast
    #pragma unroll 4
    for (int jj = 0; jj < 64; ++jj) {
        float v0 = sj[0], v1 = sj[1], v2 = sj[2], v3 = sj[3];
        float v4 = sj[4], v5 = sj[5], v6 = sj[6], v7 = sj[7];
        sj += KD_;
        float d0 = fabsf(mi[0][0] - v0) + fabsf(mi[0][1] - v1)
                 + fabsf(mi[0][2] - v2) + fabsf(mi[0][3] - v3)
                 + fabsf(mi[0][4] - v4) + fabsf(mi[0][5] - v5)
                 + fabsf(mi[0][6] - v6) + fabsf(mi[0][7] - v7);
        float d1 = fabsf(mi[1][0] - v0) + fabsf(mi[1][1] - v1)
                 + fabsf(mi[1][2] - v2) + fabsf(mi[1][3] - v3)
                 + fabsf(mi[1][4] - v4) + fabsf(mi[1][5] - v5)
                 + fabsf(mi[1][6] - v6) + fabsf(mi[1][7] - v7);
        acc0 += __expf(-d0);
        acc1 += __expf(-d1);
    }
    s2[w][lane]      = acc0;
    s2[w][lane + 64] = acc1;
    __syncthreads();

    if (t < 128) {
        float v = 0.f;
        #pragma unroll
        for (int ww = 0; ww < 8; ++ww) v += s2[ww][t];
        out[(ic * 128 + t) * ROW_ + IN_ + o] = v;
    }
}

extern "C" void kernel_launch(void* const* d_in, const int* in_sizes, int n_in,
                              void* d_out, int out_size, void* d_ws, size_t ws_size,
                              hipStream_t stream) {
    const float* x = (const float*)d_in[0];   // [512, 512]
    const float* T = (const float*)d_in[1];   // [512, 64, 8]
    float* out = (float*)d_out;               // [512, 576]
    float* Mt  = (float*)d_ws;                // [64][512][8] fp32, 1 MB

    void* args[] = { (void*)&x, (void*)&T, (void*)&out, (void*)&Mt };
    hipLaunchCooperativeKernel((void*)fused_coop_kernel,
                               dim3(256), dim3(512), args, 0, stream);
}

// Round 7
// 73.262 us; speedup vs baseline: 1.8935x; 1.8935x over previous
//
#include <hip/hip_runtime.h>

// MinibatchDiscrimination: B=512, IN=512, OUT=64, KD=8 (fp32 in/out)
// out[i, 0:512] = x[i, :]
// out[i, 512+o] = sum_j exp(-sum_k |M[i,o,k] - M[j,o,k]|),  M = x @ T
//
// R7: two kernels (R4 structure — best so far), gemm latency-hiding fixed.
//  K1 gemm : grid 256 = (ib 8 x nb 32), 512 thr = 8 waves/CU.
//            All waves stage T[k][n0..n0+16) -> LDS bf16 transposed.
//            Waves 0-3: MFMA 16x16x32 (A = x fp32 from global, packed in-reg)
//            Waves 4-7: x -> out[:,0:512) copy (overlaps MFMA latency).
//            C -> LDS -> fully-coalesced float4 Mt stores (2 o-slices/block).
//  K2 pairs: grid 256 = (o 64 x ic 4), 512 thr. Full 16KB o-slice in LDS,
//            wave-uniform broadcast reads, 2 i/thread, cross-wave LDS
//            reduction, exclusive plain store. No atomics, no side jobs.

#define B_    512
#define IN_   512
#define OUT_  64
#define KD_   8
#define ROW_  576
#define ROW4_ 144

typedef short short8 __attribute__((ext_vector_type(8)));
typedef float f32x4  __attribute__((ext_vector_type(4)));

__device__ __forceinline__ unsigned short f2bf(float f) {
    return (unsigned short)((__float_as_uint(f) + 0x8000u) >> 16);
}
__device__ __forceinline__ unsigned pack_bf2(float lo, float hi) {
    unsigned a = (__float_as_uint(lo) + 0x8000u) >> 16;
    unsigned b = (__float_as_uint(hi) + 0x8000u) & 0xFFFF0000u;
    return a | b;
}

// ---------------- K1: fused transpose + GEMM + x-copy -----------------------
__global__ __launch_bounds__(512)
void gemm_kernel(const float* __restrict__ x, const float* __restrict__ T,
                 float* __restrict__ Mt, float* __restrict__ out) {
    __shared__ unsigned short Tt[16][520];   // 16640 B, bf16 T-slice transposed
    __shared__ float Cs[64][17];             // 4352 B, C staging for coalesced Mt
    int t  = threadIdx.x;
    int bx = blockIdx.x;
    int nb = bx & 31, ib = bx >> 5;
    int n0 = nb * 16;

    // stage Tt[c][k] = bf16(T[k][n0+c]) with all 8 waves
    {
        int c  = t & 15;
        int kb = t >> 4;                     // 0..31
        #pragma unroll
        for (int p = 0; p < 16; ++p) {
            int k = kb + p * 32;
            Tt[c][k] = f2bf(T[k * 512 + n0 + c]);
        }
    }
    __syncthreads();

    int lane = t & 63, w = t >> 6;
    int r = lane & 15, q = lane >> 4;

    if (w < 4) {
        // MFMA: wave w owns i-rows [ib*64 + w*16, +16)
        int i0 = ib * 64 + w * 16;
        const float* pa = x + (i0 + r) * 512 + q * 8;
        f32x4 acc = {0.f, 0.f, 0.f, 0.f};
        #pragma unroll
        for (int kt = 0; kt < 16; ++kt) {
            float4 f0 = *(const float4*)(pa + kt * 32);
            float4 f1 = *(const float4*)(pa + kt * 32 + 4);
            union { unsigned u[4]; short8 v; } A;
            A.u[0] = pack_bf2(f0.x, f0.y);
            A.u[1] = pack_bf2(f0.z, f0.w);
            A.u[2] = pack_bf2(f1.x, f1.y);
            A.u[3] = pack_bf2(f1.z, f1.w);
            short8 Bv = *(const short8*)&Tt[r][q * 8 + kt * 32];
            acc = __builtin_amdgcn_mfma_f32_16x16x32_bf16(A.v, Bv, acc, 0, 0, 0);
        }
        // C/D map: value rr of lane -> row q*4+rr, col r
        #pragma unroll
        for (int rr = 0; rr < 4; ++rr)
            Cs[w * 16 + q * 4 + rr][r] = acc[rr];
    } else {
        // x -> out cols [0,512): 256 float4 per block, overlaps MFMA latency
        int v  = bx * 256 + (t - 256);       // [0, 65536)
        int i  = v >> 7;
        int c4 = v & 127;
        ((float4*)out)[i * ROW4_ + c4] = ((const float4*)x)[v];
    }
    __syncthreads();

    // coalesced Mt write: this block owns o-slices o = nb*2 + h, rows ib*64..+64
    if (t < 256) {
        int h   = t >> 7;                    // 0..1
        int idx = t & 127;
        int ii  = idx >> 1;                  // 0..63
        int kq  = (idx & 1) * 4;             // 0 or 4
        int o   = nb * 2 + h;
        float4 v;
        v.x = Cs[ii][h * 8 + kq + 0];
        v.y = Cs[ii][h * 8 + kq + 1];
        v.z = Cs[ii][h * 8 + kq + 2];
        v.w = Cs[ii][h * 8 + kq + 3];
        *(float4*)(Mt + o * (B_ * KD_) + (ib * 64 + ii) * KD_ + kq) = v;
    }
}

// ---------------- K2: all-pairs L1 + exp ------------------------------------
__global__ __launch_bounds__(512)
void pairs_kernel(const float* __restrict__ Mt, float* __restrict__ out) {
    __shared__ float s[B_][KD_];             // 16 KB: full o-slice
    __shared__ float s2[8][128];             // 4 KB: per-wave partials
    int t  = threadIdx.x;
    int bx = blockIdx.x;
    int o  = bx >> 2;
    int ic = bx & 3;
    const float* base = Mt + o * (B_ * KD_);

    ((float4*)s)[t]       = ((const float4*)base)[t];
    ((float4*)s)[t + 512] = ((const float4*)base)[t + 512];
    __syncthreads();

    int lane = t & 63, w = t >> 6;
    float mi[2][KD_];
    #pragma unroll
    for (int ii = 0; ii < 2; ++ii) {
        int i = ic * 128 + lane + ii * 64;
        float4 lo = *(const float4*)&s[i][0];
        float4 hi = *(const float4*)&s[i][4];
        mi[ii][0] = lo.x; mi[ii][1] = lo.y; mi[ii][2] = lo.z; mi[ii][3] = lo.w;
        mi[ii][4] = hi.x; mi[ii][5] = hi.y; mi[ii][6] = hi.z; mi[ii][7] = hi.w;
    }

    float acc0 = 0.f, acc1 = 0.f;
    const float* sj = &s[w * 64][0];         // wave-uniform -> LDS broadcast
    #pragma unroll 4
    for (int jj = 0; jj < 64; ++jj) {
        float v0 = sj[0], v1 = sj[1], v2 = sj[2], v3 = sj[3];
        float v4 = sj[4], v5 = sj[5], v6 = sj[6], v7 = sj[7];
        sj += KD_;
        float d0 = fabsf(mi[0][0] - v0) + fabsf(mi[0][1] - v1)
                 + fabsf(mi[0][2] - v2) + fabsf(mi[0][3] - v3)
                 + fabsf(mi[0][4] - v4) + fabsf(mi[0][5] - v5)
                 + fabsf(mi[0][6] - v6) + fabsf(mi[0][7] - v7);
        float d1 = fabsf(mi[1][0] - v0) + fabsf(mi[1][1] - v1)
                 + fabsf(mi[1][2] - v2) + fabsf(mi[1][3] - v3)
                 + fabsf(mi[1][4] - v4) + fabsf(mi[1][5] - v5)
                 + fabsf(mi[1][6] - v6) + fabsf(mi[1][7] - v7);
        acc0 += __expf(-d0);
        acc1 += __expf(-d1);
    }
    s2[w][lane]      = acc0;
    s2[w][lane + 64] = acc1;
    __syncthreads();

    if (t < 128) {
        float v = 0.f;
        #pragma unroll
        for (int ww = 0; ww < 8; ++ww) v += s2[ww][t];
        out[(ic * 128 + t) * ROW_ + IN_ + o] = v;
    }
}

extern "C" void kernel_launch(void* const* d_in, const int* in_sizes, int n_in,
                              void* d_out, int out_size, void* d_ws, size_t ws_size,
                              hipStream_t stream) {
    const float* x = (const float*)d_in[0];   // [512, 512]
    const float* T = (const float*)d_in[1];   // [512, 64, 8]
    float* out = (float*)d_out;               // [512, 576]
    float* Mt  = (float*)d_ws;                // [64][512][8] fp32, 1 MB

    gemm_kernel<<<256, 512, 0, stream>>>(x, T, Mt, out);
    pairs_kernel<<<256, 512, 0, stream>>>(Mt, out);
}